// Round 2
// baseline (173.299 us; speedup 1.0000x reference)
//
#include <hip/hip_runtime.h>
#include <math.h>

// Problem constants (fixed by the reference file)
#define B_     32
#define T_     2048
#define H_     1024
#define WIDTH_ 32        // max(32, 45000 // (1024+512)) = 32
#define TOTAL_ 512       // K_C + K_E
#define TOPK_  8

// ---------------------------------------------------------------------------
// Kernel 1: per-batch-row head computation -> 32 x 1024 update table in ws
// ---------------------------------------------------------------------------
__global__ __launch_bounds__(256) void head_kernel(
    const float* __restrict__ hidden,   // (B, T, H)
    const float* __restrict__ W1,       // (H, WIDTH)
    const float* __restrict__ b1,       // (WIDTH)
    const float* __restrict__ W2,       // (WIDTH, TOTAL)
    const float* __restrict__ b2,       // (TOTAL)
    const float* __restrict__ Dc,       // (256, H)
    const float* __restrict__ De,       // (256, H)
    const float* __restrict__ temp,     // scalar
    float* __restrict__ upd)            // (B, H) output update table
{
    __shared__ float s_cls[H_];
    __shared__ float s_h1[WIDTH_];
    __shared__ float s_logits[TOTAL_];
    __shared__ float s_red[256];
    __shared__ int   s_redi[256];
    __shared__ float s_u[H_];
    __shared__ int   s_tidx[TOPK_];
    __shared__ float s_tval[TOPK_];

    const int b = blockIdx.x;
    const int t = threadIdx.x;

    // ---- load cls = hidden[b, 0, :] into LDS ----
    const float* cls = hidden + (size_t)b * T_ * H_;
    for (int h = t; h < H_; h += 256) s_cls[h] = cls[h];
    __syncthreads();

    // ---- h1 = relu(cls @ W1 + b1): 32 groups of 8 threads ----
    {
        const int j    = t >> 3;   // 0..31 output index
        const int lane = t & 7;
        float acc = 0.f;
        for (int h = lane; h < H_; h += 8)
            acc += s_cls[h] * W1[h * WIDTH_ + j];
        // reduce across the 8 lanes of the group (contiguous within wave)
        for (int off = 4; off >= 1; off >>= 1)
            acc += __shfl_down(acc, off, 8);
        if (lane == 0) s_h1[j] = fmaxf(acc + b1[j], 0.f);
    }
    __syncthreads();

    // ---- logits = (h1 @ W2 + b2) / |temp| ----
    const float invT = 1.0f / fabsf(temp[0]);
    for (int i = t; i < TOTAL_; i += 256) {
        float acc = b2[i];
        #pragma unroll
        for (int j = 0; j < WIDTH_; j++)
            acc += s_h1[j] * W2[j * TOTAL_ + i];
        s_logits[i] = acc * invT;
    }
    __syncthreads();

    // ---- softmax statistics: global max, then Z = sum(exp(l - max)) ----
    float m = -INFINITY;
    for (int i = t; i < TOTAL_; i += 256) m = fmaxf(m, s_logits[i]);
    s_red[t] = m;
    __syncthreads();
    for (int s = 128; s >= 1; s >>= 1) {
        if (t < s) s_red[t] = fmaxf(s_red[t], s_red[t + s]);
        __syncthreads();
    }
    const float gmax = s_red[0];
    __syncthreads();

    float sum = 0.f;
    for (int i = t; i < TOTAL_; i += 256) sum += expf(s_logits[i] - gmax);
    s_red[t] = sum;
    __syncthreads();
    for (int s = 128; s >= 1; s >>= 1) {
        if (t < s) s_red[t] += s_red[t + s];
        __syncthreads();
    }
    const float invZ = 1.0f / s_red[0];
    __syncthreads();

    // ---- top-8 by logit (== top-8 by prob), tie-break to lower index ----
    for (int k = 0; k < TOPK_; k++) {
        float bv = -INFINITY;
        int   bi = 0x7fffffff;
        for (int i = t; i < TOTAL_; i += 256) {
            float v = s_logits[i];
            if (v > bv) { bv = v; bi = i; }   // strict > keeps lower index
        }
        s_red[t]  = bv;
        s_redi[t] = bi;
        __syncthreads();
        for (int s = 128; s >= 1; s >>= 1) {
            if (t < s) {
                float ov = s_red[t + s]; int oi = s_redi[t + s];
                if (ov > s_red[t] || (ov == s_red[t] && oi < s_redi[t])) {
                    s_red[t] = ov; s_redi[t] = oi;
                }
            }
            __syncthreads();
        }
        if (t == 0) {
            int idx = s_redi[0];
            s_tidx[k] = idx;
            s_tval[k] = expf(s_red[0] - gmax) * invZ;  // prob value
            s_logits[idx] = -INFINITY;                 // remove from pool
        }
        __syncthreads();
    }

    // ---- update = sum_k prob_k * dict[idx_k, :] ----
    for (int h = t; h < H_; h += 256) {
        float acc = 0.f;
        #pragma unroll
        for (int k = 0; k < TOPK_; k++) {
            const int idx = s_tidx[k];
            const float* row = (idx < 256) ? (Dc + (size_t)idx * H_)
                                           : (De + (size_t)(idx - 256) * H_);
            acc += s_tval[k] * row[h];
        }
        s_u[h] = acc;
    }
    __syncthreads();

    // ---- L2 norm over 1024 elements ----
    float ss = 0.f;
    for (int h = t; h < H_; h += 256) ss += s_u[h] * s_u[h];
    s_red[t] = ss;
    __syncthreads();
    for (int s = 128; s >= 1; s >>= 1) {
        if (t < s) s_red[t] += s_red[t + s];
        __syncthreads();
    }
    const float norm = sqrtf(s_red[0]);
    // final scale: / (norm + 1e-12) / sqrt(H)
    const float scale = 1.0f / ((norm + 1e-12f) * 32.0f);
    for (int h = t; h < H_; h += 256)
        upd[(size_t)b * H_ + h] = s_u[h] * scale;
}

// ---------------------------------------------------------------------------
// Kernel 2: out = hidden + upd[b] broadcast over T (pure streaming, float4)
// ---------------------------------------------------------------------------
__global__ __launch_bounds__(256) void add_kernel(
    const float* __restrict__ hidden,
    const float* __restrict__ upd,      // (B, H)
    float* __restrict__ out,
    size_t n4)                           // total float4 count
{
    const size_t stride = (size_t)gridDim.x * blockDim.x;
    for (size_t i = (size_t)blockIdx.x * blockDim.x + threadIdx.x; i < n4; i += stride) {
        float4 hv = ((const float4*)hidden)[i];
        const size_t e = i << 2;                  // element index
        const size_t b = e >> 21;                 // / (T*H) = / 2^21
        const int    h = (int)(e & (H_ - 1));     // % 1024
        const float4 uv = *(const float4*)(upd + b * H_ + h);
        hv.x += uv.x; hv.y += uv.y; hv.z += uv.z; hv.w += uv.w;
        ((float4*)out)[i] = hv;
    }
}

// ---------------------------------------------------------------------------
extern "C" void kernel_launch(void* const* d_in, const int* in_sizes, int n_in,
                              void* d_out, int out_size, void* d_ws, size_t ws_size,
                              hipStream_t stream) {
    const float* hidden = (const float*)d_in[0];
    const float* W1     = (const float*)d_in[1];
    const float* b1     = (const float*)d_in[2];
    const float* W2     = (const float*)d_in[3];
    const float* b2     = (const float*)d_in[4];
    const float* Dc     = (const float*)d_in[5];
    const float* De     = (const float*)d_in[6];
    const float* temp   = (const float*)d_in[7];

    float* out = (float*)d_out;
    float* upd = (float*)d_ws;   // 32*1024*4 = 128 KB scratch

    head_kernel<<<B_, 256, 0, stream>>>(hidden, W1, b1, W2, b2, Dc, De, temp, upd);

    const size_t n4 = (size_t)B_ * T_ * H_ / 4;  // 16,777,216 float4
    add_kernel<<<2048, 256, 0, stream>>>(hidden, upd, out, n4);
}